// Round 9
// baseline (106.757 us; speedup 1.0000x reference)
//
#include <hip/hip_runtime.h>

#define H_IMG 128
#define W_IMG 48
#define CIN   64
#define DM    32
#define NH    8
#define NPIX  6144
#define SSEG  4

// 0.5 (dh^-0.5) * log2(e): fold exp->exp2 conversion into q at conv time
#define Q_SCALE 0.7213475204444817f

typedef _Float16 half4 __attribute__((ext_vector_type(4)));
typedef __fp16   fp16x2 __attribute__((ext_vector_type(2)));
typedef float    f32x4 __attribute__((ext_vector_type(4)));

__device__ __forceinline__ float fexp2(float x) { return __builtin_amdgcn_exp2f(x); }

__device__ __forceinline__ half4 exp_pack(f32x4 s) {
    fp16x2 lo = __builtin_amdgcn_cvt_pkrtz(fexp2(s[0]), fexp2(s[1]));
    fp16x2 hi = __builtin_amdgcn_cvt_pkrtz(fexp2(s[2]), fexp2(s[3]));
    half4 p;
    p[0] = (_Float16)lo[0]; p[1] = (_Float16)lo[1];
    p[2] = (_Float16)hi[0]; p[3] = (_Float16)hi[1];
    return p;
}

// ---------------------------------------------------------------------------
// Kernel 1a: QKV conv partials, split over (m, dy, ci-half, cg, pixgroup).
// grid = 3m * 3dy * nci * 4cg * 24; 256 thr; thread = pixel, 8 channels.
// Partial layout P[(m*3+dyg)*nci+cih][ch(32)][pix] f32 (ch-plane-major,
// coalesced 4B writes/reads).  No bias here (added in finalize).
// ---------------------------------------------------------------------------
__global__ __launch_bounds__(256) void qkv_partial_kernel(
    const float* __restrict__ x,
    const float* __restrict__ wq, const float* __restrict__ wk,
    const float* __restrict__ wv,
    float* __restrict__ P, int nci)
{
    int tmp = blockIdx.x;
    const int pg  = tmp % 24; tmp /= 24;
    const int cg  = tmp % 4;  tmp /= 4;
    const int cih = tmp % nci; tmp /= nci;
    const int dyg = tmp % 3;
    const int m   = tmp / 3;

    const int pix = pg * 256 + threadIdx.x;
    const int y   = pix / W_IMG;
    const int x0  = pix % W_IMG;

    const float* w = (m == 0) ? wq : (m == 1) ? wk : wv;
    const int cspan = CIN / nci;
    const int ci0   = cih * cspan;

    float acc[8] = {0.f, 0.f, 0.f, 0.f, 0.f, 0.f, 0.f, 0.f};

    const int yy = y + dyg - 1;
    if (yy >= 0 && yy < H_IMG) {
        #pragma unroll
        for (int dx = -1; dx <= 1; ++dx) {
            const int xc = x0 + dx;
            if (xc < 0 || xc >= W_IMG) continue;
            const float* xp = x + (yy * W_IMG + xc) * CIN + ci0;
            const float* wp = w + (dyg * 3 + (dx + 1)) * CIN * DM + ci0 * DM + cg * 8;
            #pragma unroll
            for (int ci = 0; ci < 64 / 2; ci += 4) {   // cspan <= 32 when nci=2
                if (ci >= cspan) break;
                const float4 xv = *reinterpret_cast<const float4*>(xp + ci);
                #pragma unroll
                for (int j = 0; j < 8; ++j) {
                    acc[j] += xv.x * wp[(ci + 0) * DM + j];
                    acc[j] += xv.y * wp[(ci + 1) * DM + j];
                    acc[j] += xv.z * wp[(ci + 2) * DM + j];
                    acc[j] += xv.w * wp[(ci + 3) * DM + j];
                }
            }
            if (cspan > 32) {   // nci==1: second half
                #pragma unroll
                for (int ci = 32; ci < 64; ci += 4) {
                    const float4 xv = *reinterpret_cast<const float4*>(xp + ci);
                    #pragma unroll
                    for (int j = 0; j < 8; ++j) {
                        acc[j] += xv.x * wp[(ci + 0) * DM + j];
                        acc[j] += xv.y * wp[(ci + 1) * DM + j];
                        acc[j] += xv.z * wp[(ci + 2) * DM + j];
                        acc[j] += xv.w * wp[(ci + 3) * DM + j];
                    }
                }
            }
        }
    }

    float* pp = P + ((size_t)(((m * 3 + dyg) * nci + cih) * DM + cg * 8)) * NPIX + pix;
    #pragma unroll
    for (int j = 0; j < 8; ++j) pp[(size_t)j * NPIX] = acc[j];
}

// ---------------------------------------------------------------------------
// Kernel 1b: sum QKV partials + bias, emit f16 hi/lo q,k and 5-plane vT.
// grid = 3m * 4cg * 24; thread = pixel, 8 channels (2 heads).
// ---------------------------------------------------------------------------
__global__ __launch_bounds__(256) void qkv_finalize_kernel(
    const float* __restrict__ P,
    const float* __restrict__ bq, const float* __restrict__ bk,
    const float* __restrict__ bv,
    half4* __restrict__ qhi, half4* __restrict__ qlo,
    half4* __restrict__ khi, half4* __restrict__ klo,
    _Float16* __restrict__ vT, int nci)
{
    int tmp = blockIdx.x;
    const int pg = tmp % 24; tmp /= 24;
    const int cg = tmp % 4;
    const int m  = tmp / 4;
    const int pix = pg * 256 + threadIdx.x;

    const float* b = (m == 0) ? bq : (m == 1) ? bk : bv;

    float acc[8];
    #pragma unroll
    for (int j = 0; j < 8; ++j) acc[j] = b[cg * 8 + j];

    for (int s = 0; s < 3 * nci; ++s) {
        const float* pp = P + ((size_t)((m * 3 * nci + s) * DM + cg * 8)) * NPIX + pix;
        #pragma unroll
        for (int j = 0; j < 8; ++j) acc[j] += pp[(size_t)j * NPIX];
    }

    const float s = (m == 0) ? Q_SCALE : 1.0f;

    #pragma unroll
    for (int hh = 0; hh < 2; ++hh) {
        const int h = cg * 2 + hh;
        float a0 = acc[hh*4+0]*s, a1 = acc[hh*4+1]*s,
              a2 = acc[hh*4+2]*s, a3 = acc[hh*4+3]*s;
        if (m == 2) {
            vT[(h*5+0)*NPIX + pix] = (_Float16)a0;
            vT[(h*5+1)*NPIX + pix] = (_Float16)a1;
            vT[(h*5+2)*NPIX + pix] = (_Float16)a2;
            vT[(h*5+3)*NPIX + pix] = (_Float16)a3;
            vT[(h*5+4)*NPIX + pix] = (_Float16)1.0f;
        } else {
            half4 hi = { (_Float16)a0, (_Float16)a1, (_Float16)a2, (_Float16)a3 };
            half4 lo = { (_Float16)(a0 - (float)hi[0]),
                         (_Float16)(a1 - (float)hi[1]),
                         (_Float16)(a2 - (float)hi[2]),
                         (_Float16)(a3 - (float)hi[3]) };
            half4* dhi = (m == 0) ? qhi : khi;
            half4* dlo = (m == 0) ? qlo : klo;
            dhi[h*NPIX + pix] = hi;
            dlo[h*NPIX + pix] = lo;
        }
    }
}

// ---------------------------------------------------------------------------
// Kernel 2a: MFMA local attention (split-K partials) — unchanged from R8.
// ---------------------------------------------------------------------------
__global__ __launch_bounds__(256) void attn_mfma_kernel(
    const half4* __restrict__ qhi, const half4* __restrict__ qlo,
    const half4* __restrict__ khi, const half4* __restrict__ klo,
    const _Float16* __restrict__ vT,
    float* __restrict__ partA,     // [SSEG][16hg][3072 q][4]
    float* __restrict__ partS)     // [SSEG][16hg][3072 q]
{
    const int hg   = blockIdx.x / 96;
    const int rest = blockIdx.x % 96;
    const int seg  = __builtin_amdgcn_readfirstlane(rest / 24);
    const int qg   = rest % 24;
    const int wav  = __builtin_amdgcn_readfirstlane(threadIdx.x >> 6);
    const int qtA  = (qg * 4 + wav) * 2;      // tiles qtA, qtA+1
    const int h    = hg >> 1, g = hg & 1;
    const int lane = threadIdx.x & 63;
    const int c    = lane & 15;
    const int g16  = lane >> 4;
    const int c0   = g * 16;

    half4 qfA = {}, qfB = {};
    {
        const half4* qsrc = (g16 == 1) ? qlo : qhi;
        const int qa  = qtA * 16 + c;
        const int qay = qa / 24;
        const int qb  = qa + 16;
        const int qby = qb / 24;
        if (g16 < 3) {
            qfA = qsrc[h * NPIX + qay * W_IMG + g * 24 + (qa - qay * 24)];
            qfB = qsrc[h * NPIX + qby * W_IMG + g * 24 + (qb - qby * 24)];
        }
    }

    const half4* kb = ((g16 == 2) ? klo : khi) + h * NPIX + c;
    const int vplane = (c < 4) ? c : 4;
    const _Float16* vb = vT + (h * 5 + vplane) * NPIX + 4 * g16;

    const f32x4 zc = {0.f, 0.f, 0.f, 0.f};
    f32x4 oA0 = zc, oA1 = zc, oB0 = zc, oB1 = zc;

    const int r0 = seg * (H_IMG / SSEG);
    #pragma unroll 4
    for (int r = 0; r < H_IMG / SSEG; ++r) {
        const int koff = (r0 + r) * W_IMG + c0;

        const half4 k0 = kb[koff];
        const half4 k1 = kb[koff + 16];
        const half4 v0 = *reinterpret_cast<const half4*>(vb + koff);
        const half4 v1 = *reinterpret_cast<const half4*>(vb + koff + 16);

        const f32x4 sA0 = __builtin_amdgcn_mfma_f32_16x16x16f16(k0, qfA, zc, 0, 0, 0);
        const f32x4 sA1 = __builtin_amdgcn_mfma_f32_16x16x16f16(k1, qfA, zc, 0, 0, 0);
        const f32x4 sB0 = __builtin_amdgcn_mfma_f32_16x16x16f16(k0, qfB, zc, 0, 0, 0);
        const f32x4 sB1 = __builtin_amdgcn_mfma_f32_16x16x16f16(k1, qfB, zc, 0, 0, 0);

        const half4 pA0 = exp_pack(sA0);
        const half4 pA1 = exp_pack(sA1);
        const half4 pB0 = exp_pack(sB0);
        const half4 pB1 = exp_pack(sB1);

        oA0 = __builtin_amdgcn_mfma_f32_16x16x16f16(pA0, v0, oA0, 0, 0, 0);
        oA1 = __builtin_amdgcn_mfma_f32_16x16x16f16(pA1, v1, oA1, 0, 0, 0);
        oB0 = __builtin_amdgcn_mfma_f32_16x16x16f16(pB0, v0, oB0, 0, 0, 0);
        oB1 = __builtin_amdgcn_mfma_f32_16x16x16f16(pB1, v1, oB1, 0, 0, 0);
    }

    const f32x4 oA = oA0 + oA1;
    const f32x4 oB = oB0 + oB1;

    const int base = (seg * 16 + hg) * 3072;
    const int qa = base + qtA * 16 + g16 * 4;
    const int qb = qa + 16;
    if (c < 4) {
        #pragma unroll
        for (int r = 0; r < 4; ++r) partA[(qa + r) * 4 + c] = oA[r];
        #pragma unroll
        for (int r = 0; r < 4; ++r) partA[(qb + r) * 4 + c] = oB[r];
    } else if (c == 4) {
        #pragma unroll
        for (int r = 0; r < 4; ++r) partS[qa + r] = oA[r];
        #pragma unroll
        for (int r = 0; r < 4; ++r) partS[qb + r] = oB[r];
    }
}

// ---------------------------------------------------------------------------
// Kernel 2b: combine split-K partials, normalize, write att[y][x][32].
// ---------------------------------------------------------------------------
__global__ __launch_bounds__(256) void attn_reduce_kernel(
    const f32x4* __restrict__ partA4,
    const float* __restrict__ partS,
    float* __restrict__ att)
{
    const int idx = blockIdx.x * 256 + threadIdx.x;  // 0..49151
    const int hg  = idx / 3072;
    const int q   = idx % 3072;
    const int h   = hg >> 1, g = hg & 1;

    f32x4 a = {0.f, 0.f, 0.f, 0.f};
    float ss = 0.f;
    #pragma unroll
    for (int s = 0; s < SSEG; ++s) {
        a  += partA4[(s * 16 + hg) * 3072 + q];
        ss += partS [(s * 16 + hg) * 3072 + q];
    }
    const float inv = 1.0f / ss;
    const int qy = q / 24;
    const int pix = qy * W_IMG + g * 24 + (q - qy * 24);
    *reinterpret_cast<float4*>(att + pix * DM + h * 4) =
        make_float4(a[0] * inv, a[1] * inv, a[2] * inv, a[3] * inv);
}

// ---------------------------------------------------------------------------
// Kernel 3a: output conv partials, split over dy.  grid = 3dy * 8cg * 24.
// Partial layout OP[dyg][pix][64] f32.
// ---------------------------------------------------------------------------
__global__ __launch_bounds__(256) void out_partial_kernel(
    const float* __restrict__ att,
    const float* __restrict__ wo,
    float* __restrict__ OP)
{
    int tmp = blockIdx.x;
    const int pg  = tmp % 24; tmp /= 24;
    const int cg  = tmp % 8;
    const int dyg = tmp / 8;
    const int pix = pg * 256 + threadIdx.x;
    const int y   = pix / W_IMG;
    const int x0  = pix % W_IMG;

    float acc[8] = {0.f, 0.f, 0.f, 0.f, 0.f, 0.f, 0.f, 0.f};

    const int yy = y + dyg - 1;
    if (yy >= 0 && yy < H_IMG) {
        #pragma unroll
        for (int dx = -1; dx <= 1; ++dx) {
            const int xc = x0 + dx;
            if (xc < 0 || xc >= W_IMG) continue;
            const float* ap = att + (yy * W_IMG + xc) * DM;
            const float* wp = wo + (dyg * 3 + (dx + 1)) * DM * 64 + cg * 8;
            #pragma unroll
            for (int ci = 0; ci < DM; ci += 4) {
                const float4 xv = *reinterpret_cast<const float4*>(ap + ci);
                #pragma unroll
                for (int j = 0; j < 8; ++j) {
                    acc[j] += xv.x * wp[(ci + 0) * 64 + j];
                    acc[j] += xv.y * wp[(ci + 1) * 64 + j];
                    acc[j] += xv.z * wp[(ci + 2) * 64 + j];
                    acc[j] += xv.w * wp[(ci + 3) * 64 + j];
                }
            }
        }
    }

    float* op = OP + ((size_t)dyg * NPIX + pix) * 64 + cg * 8;
    *reinterpret_cast<float4*>(op + 0) = make_float4(acc[0], acc[1], acc[2], acc[3]);
    *reinterpret_cast<float4*>(op + 4) = make_float4(acc[4], acc[5], acc[6], acc[7]);
}

// ---------------------------------------------------------------------------
// Kernel 3b: sum the 3 dy partials -> out.  grid = 192; thread = (pix, 8ch).
// ---------------------------------------------------------------------------
__global__ __launch_bounds__(256) void out_final_kernel(
    const float* __restrict__ OP,
    float* __restrict__ out)
{
    const int idx = blockIdx.x * 256 + threadIdx.x;  // 0..49151
    const int pix = idx >> 3;
    const int cg  = idx & 7;
    const size_t o = (size_t)pix * 64 + cg * 8;

    f32x4 a0 = {0,0,0,0}, a1 = {0,0,0,0};
    #pragma unroll
    for (int d = 0; d < 3; ++d) {
        const float* p = OP + (size_t)d * NPIX * 64 + o;
        a0 += *reinterpret_cast<const f32x4*>(p + 0);
        a1 += *reinterpret_cast<const f32x4*>(p + 4);
    }
    *reinterpret_cast<f32x4*>(out + o + 0) = a0;
    *reinterpret_cast<f32x4*>(out + o + 4) = a1;
}

// ---------------------------------------------------------------------------
extern "C" void kernel_launch(void* const* d_in, const int* in_sizes, int n_in,
                              void* d_out, int out_size, void* d_ws, size_t ws_size,
                              hipStream_t stream)
{
    const float* x  = (const float*)d_in[0];
    const float* wq = (const float*)d_in[1];
    const float* bq = (const float*)d_in[2];
    const float* wk = (const float*)d_in[3];
    const float* bk = (const float*)d_in[4];
    const float* wv = (const float*)d_in[5];
    const float* bv = (const float*)d_in[6];
    const float* wo = (const float*)d_in[7];
    float* out = (float*)d_out;

    // region A (persistent f16 buffers)
    char* base = (char*)d_ws;
    half4*    qhi = (half4*)(base + 0);
    half4*    qlo = (half4*)(base + 393216);
    half4*    khi = (half4*)(base + 786432);
    half4*    klo = (half4*)(base + 1179648);
    _Float16* vT  = (_Float16*)(base + 1572864);   // 491520 B -> A ends 2064384

    // region B/C/D/E (aliased, disjoint lifetimes), base:
    char* rb = base + 2064384;
    // choose ci split by workspace size
    const size_t needP2 = (size_t)3 * 3 * 2 * DM * NPIX * 4;   // 14155776
    const size_t tailCDE = 4718592 + 786432;                   // max(C,E)+D
    const int nci = (ws_size >= 2064384 + (needP2 > tailCDE ? needP2 : tailCDE)) ? 2 : 1;

    float* P     = (float*)rb;                         // qkv partials
    float* partA = (float*)rb;                         // attn partials (alias P)
    float* partS = (float*)(rb + 3145728);
    float* OP    = (float*)rb;                         // out-conv partials (alias C)
    float* att   = (float*)(rb + 4718592);             // 786432 B

    hipLaunchKernelGGL(qkv_partial_kernel, dim3(864 * nci), dim3(256), 0, stream,
                       x, wq, wk, wv, P, nci);

    hipLaunchKernelGGL(qkv_finalize_kernel, dim3(288), dim3(256), 0, stream,
                       P, bq, bk, bv, qhi, qlo, khi, klo, vT, nci);

    hipLaunchKernelGGL(attn_mfma_kernel, dim3(16 * 96), dim3(256), 0, stream,
                       qhi, qlo, khi, klo, vT, partA, partS);

    hipLaunchKernelGGL(attn_reduce_kernel, dim3(192), dim3(256), 0, stream,
                       (const f32x4*)partA, partS, att);

    hipLaunchKernelGGL(out_partial_kernel, dim3(576), dim3(256), 0, stream,
                       att, wo, OP);

    hipLaunchKernelGGL(out_final_kernel, dim3(192), dim3(256), 0, stream,
                       OP, out);
}

// Round 10
// 81.166 us; speedup vs baseline: 1.3153x; 1.3153x over previous
//
#include <hip/hip_runtime.h>

#define H_IMG 128
#define W_IMG 48
#define CIN   64
#define DM    32
#define NH    8
#define NPIX  6144
#define SSEG  4
#define WPAD  50
#define HPAD  130

// 0.5 (dh^-0.5) * log2(e): folded into wq/bq at convert time
#define Q_SCALE 0.7213475204444817f

typedef _Float16 half4 __attribute__((ext_vector_type(4)));
typedef __fp16   fp16x2 __attribute__((ext_vector_type(2)));
typedef float    f32x4 __attribute__((ext_vector_type(4)));

__device__ __forceinline__ float fexp2(float x) { return __builtin_amdgcn_exp2f(x); }

__device__ __forceinline__ half4 exp_pack(f32x4 s) {
    fp16x2 lo = __builtin_amdgcn_cvt_pkrtz(fexp2(s[0]), fexp2(s[1]));
    fp16x2 hi = __builtin_amdgcn_cvt_pkrtz(fexp2(s[2]), fexp2(s[3]));
    half4 p;
    p[0] = (_Float16)lo[0]; p[1] = (_Float16)lo[1];
    p[2] = (_Float16)hi[0]; p[3] = (_Float16)hi[1];
    return p;
}

// ---------------------------------------------------------------------------
// K0: setup — xpad f16 (zero border), vT ones planes, attpad zero,
// whT[m][32][576] (Q_SCALE folded into m=0), whoT[64][288].
// ---------------------------------------------------------------------------
__global__ __launch_bounds__(256) void setup_kernel(
    const float* __restrict__ x,
    const float* __restrict__ wq, const float* __restrict__ wk,
    const float* __restrict__ wv, const float* __restrict__ wo,
    _Float16* __restrict__ xpad, _Float16* __restrict__ vT,
    _Float16* __restrict__ attpad,
    _Float16* __restrict__ whT, _Float16* __restrict__ whoT)
{
    const int bid = blockIdx.x;
    const int tid = threadIdx.x;

    if (bid < 26) {                       // xpad: one padded pixel per thread
        const int pp = bid * 256 + tid;
        if (pp < HPAD * WPAD) {
            const int py = pp / WPAD, px = pp % WPAD;
            _Float16* dst = xpad + (size_t)pp * CIN;
            if (py >= 1 && py <= H_IMG && px >= 1 && px <= W_IMG) {
                const float* src = x + ((size_t)(py - 1) * W_IMG + (px - 1)) * CIN;
                #pragma unroll
                for (int c = 0; c < CIN; c += 4) {
                    const float4 v = *reinterpret_cast<const float4*>(src + c);
                    half4 hv = { (_Float16)v.x, (_Float16)v.y, (_Float16)v.z, (_Float16)v.w };
                    *reinterpret_cast<half4*>(dst + c) = hv;
                }
            } else {
                const half4 z = {};
                #pragma unroll
                for (int c = 0; c < CIN; c += 4)
                    *reinterpret_cast<half4*>(dst + c) = z;
            }
        }
    } else if (bid == 26) {               // vT ones planes (h*5+4)
        const int h = tid >> 5, chunk = tid & 31;
        _Float16* dst = vT + ((size_t)(h * 5 + 4)) * NPIX + chunk * (NPIX / 32);
        half4 ones = { (_Float16)1.0f, (_Float16)1.0f, (_Float16)1.0f, (_Float16)1.0f };
        #pragma unroll
        for (int i = 0; i < NPIX / 32; i += 4)
            *reinterpret_cast<half4*>(dst + i) = ones;
    } else if (bid < 53) {                // attpad zero
        const int pp = (bid - 27) * 256 + tid;
        if (pp < HPAD * WPAD) {
            _Float16* dst = attpad + (size_t)pp * DM;
            const half4 z = {};
            #pragma unroll
            for (int c = 0; c < DM; c += 4)
                *reinterpret_cast<half4*>(dst + c) = z;
        }
    } else if (bid < 57) {                // whT
        const int u = (bid - 53) * 256 + tid;
        if (u < 3 * 32 * 9) {
            const int m = u / 288, c = (u % 288) / 9, tap = u % 9;
            const float* w = (m == 0) ? wq : (m == 1) ? wk : wv;
            const float s = (m == 0) ? Q_SCALE : 1.0f;
            const float* src = w + (size_t)tap * CIN * DM + c;
            _Float16* dst = whT + ((size_t)(m * 32 + c)) * 576 + tap * 64;
            for (int ci = 0; ci < CIN; ++ci)
                dst[ci] = (_Float16)(src[(size_t)ci * DM] * s);
        }
    } else {                              // whoT
        const int u = (bid - 57) * 256 + tid;
        if (u < 64 * 9) {
            const int c = u / 9, tap = u % 9;
            const float* src = wo + (size_t)tap * DM * 64 + c;
            _Float16* dst = whoT + (size_t)c * 288 + tap * 32;
            for (int ci = 0; ci < DM; ++ci)
                dst[ci] = (_Float16)src[(size_t)ci * 64];
        }
    }
}

// ---------------------------------------------------------------------------
// K1: QKV conv as MFMA GEMM.  M=6144 pix, N=32 ch, K=576 (9 taps x 64ci).
// grid = 3m * 2nt * 96; block = 4 waves = 4 pixel tiles.
// A: lane(g,r) holds xpad[pix r][k=4g+j]; B: lane(g,c) holds whT[ch c][k].
// D: lane(g,c) holds out[pix 4g+reg][ch c].  Epilogue: +bias, emit q/k f16
// hi/lo (half4 per head-pixel) and 5-plane vT.
// ---------------------------------------------------------------------------
__global__ __launch_bounds__(256) void qkv_mfma_kernel(
    const _Float16* __restrict__ xpad,
    const _Float16* __restrict__ whT,
    const float* __restrict__ bq, const float* __restrict__ bk,
    const float* __restrict__ bv,
    half4* __restrict__ qhi, half4* __restrict__ qlo,
    half4* __restrict__ khi, half4* __restrict__ klo,
    _Float16* __restrict__ vT)
{
    const int m   = __builtin_amdgcn_readfirstlane(blockIdx.x / 192);
    const int nt  = __builtin_amdgcn_readfirstlane((blockIdx.x / 96) % 2);
    const int pg  = blockIdx.x % 96;
    const int wav = __builtin_amdgcn_readfirstlane(threadIdx.x >> 6);
    const int pt  = pg * 4 + wav;                 // pixel tile 0..383
    const int lane = threadIdx.x & 63;
    const int r    = lane & 15;
    const int g16  = lane >> 4;

    // A-operand per-lane base: pixel pt*16 + r
    const int p  = pt * 16 + r;
    const int y  = p / W_IMG, x0 = p % W_IMG;
    const _Float16* xb = xpad + ((size_t)y * WPAD + x0) * CIN + 4 * g16;

    // B-operand per-lane base: ch = nt*16 + (lane&15)
    const int ch = nt * 16 + r;
    const _Float16* wb = whT + ((size_t)(m * 32 + ch)) * 576 + 4 * g16;

    f32x4 a0 = {0.f, 0.f, 0.f, 0.f}, a1 = {0.f, 0.f, 0.f, 0.f};

    #pragma unroll
    for (int dy = 0; dy < 3; ++dy) {
        #pragma unroll
        for (int dx = 0; dx < 3; ++dx) {
            const int toff = (dy * WPAD + dx) * CIN;
            const int k0   = (dy * 3 + dx) * 64;
            #pragma unroll
            for (int cb = 0; cb < 4; ++cb) {
                const half4 xa = *reinterpret_cast<const half4*>(xb + toff + cb * 16);
                const half4 wf = *reinterpret_cast<const half4*>(wb + k0 + cb * 16);
                if ((((dy * 3 + dx) * 4) + cb) & 1)
                    a1 = __builtin_amdgcn_mfma_f32_16x16x16f16(xa, wf, a1, 0, 0, 0);
                else
                    a0 = __builtin_amdgcn_mfma_f32_16x16x16f16(xa, wf, a0, 0, 0, 0);
            }
        }
    }

    const float* b = (m == 0) ? bq : (m == 1) ? bk : bv;
    const float bias = b[ch] * ((m == 0) ? Q_SCALE : 1.0f);
    f32x4 o = a0 + a1;
    #pragma unroll
    for (int j = 0; j < 4; ++j) o[j] += bias;

    const int pix0 = pt * 16 + 4 * g16;           // 4 consecutive pixels
    if (m == 2) {
        const int plane = (ch >> 2) * 5 + (ch & 3);
        half4 hv = { (_Float16)o[0], (_Float16)o[1], (_Float16)o[2], (_Float16)o[3] };
        *reinterpret_cast<half4*>(vT + (size_t)plane * NPIX + pix0) = hv;
    } else {
        _Float16* dhi = (_Float16*)((m == 0) ? qhi : khi);
        _Float16* dlo = (_Float16*)((m == 0) ? qlo : klo);
        const int h = ch >> 2, d = ch & 3;
        #pragma unroll
        for (int j = 0; j < 4; ++j) {
            const float val = o[j];
            const _Float16 hi = (_Float16)val;
            const _Float16 lo = (_Float16)(val - (float)hi);
            const size_t idx = ((size_t)h * NPIX + pix0 + j) * 4 + d;
            dhi[idx] = hi;
            dlo[idx] = lo;
        }
    }
}

// ---------------------------------------------------------------------------
// K2: MFMA local attention (split-K partials) — unchanged from R8 (validated).
// ---------------------------------------------------------------------------
__global__ __launch_bounds__(256) void attn_mfma_kernel(
    const half4* __restrict__ qhi, const half4* __restrict__ qlo,
    const half4* __restrict__ khi, const half4* __restrict__ klo,
    const _Float16* __restrict__ vT,
    float* __restrict__ partA,     // [SSEG][16hg][3072 q][4]
    float* __restrict__ partS)     // [SSEG][16hg][3072 q]
{
    const int hg   = blockIdx.x / 96;
    const int rest = blockIdx.x % 96;
    const int seg  = __builtin_amdgcn_readfirstlane(rest / 24);
    const int qg   = rest % 24;
    const int wav  = __builtin_amdgcn_readfirstlane(threadIdx.x >> 6);
    const int qtA  = (qg * 4 + wav) * 2;      // tiles qtA, qtA+1
    const int h    = hg >> 1, g = hg & 1;
    const int lane = threadIdx.x & 63;
    const int c    = lane & 15;
    const int g16  = lane >> 4;
    const int c0   = g * 16;

    half4 qfA = {}, qfB = {};
    {
        const half4* qsrc = (g16 == 1) ? qlo : qhi;
        const int qa  = qtA * 16 + c;
        const int qay = qa / 24;
        const int qb  = qa + 16;
        const int qby = qb / 24;
        if (g16 < 3) {
            qfA = qsrc[h * NPIX + qay * W_IMG + g * 24 + (qa - qay * 24)];
            qfB = qsrc[h * NPIX + qby * W_IMG + g * 24 + (qb - qby * 24)];
        }
    }

    const half4* kb = ((g16 == 2) ? klo : khi) + h * NPIX + c;
    const int vplane = (c < 4) ? c : 4;
    const _Float16* vb = vT + (h * 5 + vplane) * NPIX + 4 * g16;

    const f32x4 zc = {0.f, 0.f, 0.f, 0.f};
    f32x4 oA0 = zc, oA1 = zc, oB0 = zc, oB1 = zc;

    const int r0 = seg * (H_IMG / SSEG);
    #pragma unroll 4
    for (int r = 0; r < H_IMG / SSEG; ++r) {
        const int koff = (r0 + r) * W_IMG + c0;

        const half4 k0 = kb[koff];
        const half4 k1 = kb[koff + 16];
        const half4 v0 = *reinterpret_cast<const half4*>(vb + koff);
        const half4 v1 = *reinterpret_cast<const half4*>(vb + koff + 16);

        const f32x4 sA0 = __builtin_amdgcn_mfma_f32_16x16x16f16(k0, qfA, zc, 0, 0, 0);
        const f32x4 sA1 = __builtin_amdgcn_mfma_f32_16x16x16f16(k1, qfA, zc, 0, 0, 0);
        const f32x4 sB0 = __builtin_amdgcn_mfma_f32_16x16x16f16(k0, qfB, zc, 0, 0, 0);
        const f32x4 sB1 = __builtin_amdgcn_mfma_f32_16x16x16f16(k1, qfB, zc, 0, 0, 0);

        const half4 pA0 = exp_pack(sA0);
        const half4 pA1 = exp_pack(sA1);
        const half4 pB0 = exp_pack(sB0);
        const half4 pB1 = exp_pack(sB1);

        oA0 = __builtin_amdgcn_mfma_f32_16x16x16f16(pA0, v0, oA0, 0, 0, 0);
        oA1 = __builtin_amdgcn_mfma_f32_16x16x16f16(pA1, v1, oA1, 0, 0, 0);
        oB0 = __builtin_amdgcn_mfma_f32_16x16x16f16(pB0, v0, oB0, 0, 0, 0);
        oB1 = __builtin_amdgcn_mfma_f32_16x16x16f16(pB1, v1, oB1, 0, 0, 0);
    }

    const f32x4 oA = oA0 + oA1;
    const f32x4 oB = oB0 + oB1;

    const int base = (seg * 16 + hg) * 3072;
    const int qa = base + qtA * 16 + g16 * 4;
    const int qb = qa + 16;
    if (c < 4) {
        #pragma unroll
        for (int r = 0; r < 4; ++r) partA[(qa + r) * 4 + c] = oA[r];
        #pragma unroll
        for (int r = 0; r < 4; ++r) partA[(qb + r) * 4 + c] = oB[r];
    } else if (c == 4) {
        #pragma unroll
        for (int r = 0; r < 4; ++r) partS[qa + r] = oA[r];
        #pragma unroll
        for (int r = 0; r < 4; ++r) partS[qb + r] = oB[r];
    }
}

// ---------------------------------------------------------------------------
// K3: combine split-K partials, normalize, write f16 attpad[py][px][32].
// ---------------------------------------------------------------------------
__global__ __launch_bounds__(256) void attn_reduce_kernel(
    const f32x4* __restrict__ partA4,
    const float* __restrict__ partS,
    _Float16* __restrict__ attpad)
{
    const int idx = blockIdx.x * 256 + threadIdx.x;  // 0..49151
    const int hg  = idx / 3072;
    const int q   = idx % 3072;
    const int h   = hg >> 1, g = hg & 1;

    f32x4 a = {0.f, 0.f, 0.f, 0.f};
    float ss = 0.f;
    #pragma unroll
    for (int s = 0; s < SSEG; ++s) {
        a  += partA4[(s * 16 + hg) * 3072 + q];
        ss += partS [(s * 16 + hg) * 3072 + q];
    }
    const float inv = 1.0f / ss;
    const int qy = q / 24;
    const int qx = g * 24 + (q - qy * 24);
    half4 hv = { (_Float16)(a[0] * inv), (_Float16)(a[1] * inv),
                 (_Float16)(a[2] * inv), (_Float16)(a[3] * inv) };
    *reinterpret_cast<half4*>(
        attpad + ((size_t)(qy + 1) * WPAD + qx + 1) * DM + h * 4) = hv;
}

// ---------------------------------------------------------------------------
// K4: output conv as MFMA GEMM.  M=6144, N=64, K=288 (9 taps x 32ci).
// grid = 4nt * 96; block = 4 waves = 4 pixel tiles.  No bias; f32 out.
// ---------------------------------------------------------------------------
__global__ __launch_bounds__(256) void out_mfma_kernel(
    const _Float16* __restrict__ attpad,
    const _Float16* __restrict__ whoT,
    float* __restrict__ out)
{
    const int nt  = __builtin_amdgcn_readfirstlane(blockIdx.x / 96);
    const int pg  = blockIdx.x % 96;
    const int wav = __builtin_amdgcn_readfirstlane(threadIdx.x >> 6);
    const int pt  = pg * 4 + wav;
    const int lane = threadIdx.x & 63;
    const int r    = lane & 15;
    const int g16  = lane >> 4;

    const int p  = pt * 16 + r;
    const int y  = p / W_IMG, x0 = p % W_IMG;
    const _Float16* ab = attpad + ((size_t)y * WPAD + x0) * DM + 4 * g16;

    const int ch = nt * 16 + r;
    const _Float16* wb = whoT + (size_t)ch * 288 + 4 * g16;

    f32x4 a0 = {0.f, 0.f, 0.f, 0.f}, a1 = {0.f, 0.f, 0.f, 0.f};

    #pragma unroll
    for (int dy = 0; dy < 3; ++dy) {
        #pragma unroll
        for (int dx = 0; dx < 3; ++dx) {
            const int toff = (dy * WPAD + dx) * DM;
            const int k0   = (dy * 3 + dx) * 32;
            #pragma unroll
            for (int cb = 0; cb < 2; ++cb) {
                const half4 xa = *reinterpret_cast<const half4*>(ab + toff + cb * 16);
                const half4 wf = *reinterpret_cast<const half4*>(wb + k0 + cb * 16);
                if ((((dy * 3 + dx) * 2) + cb) & 1)
                    a1 = __builtin_amdgcn_mfma_f32_16x16x16f16(xa, wf, a1, 0, 0, 0);
                else
                    a0 = __builtin_amdgcn_mfma_f32_16x16x16f16(xa, wf, a0, 0, 0, 0);
            }
        }
    }

    const f32x4 o = a0 + a1;
    const int pix0 = pt * 16 + 4 * g16;
    #pragma unroll
    for (int j = 0; j < 4; ++j)
        out[(size_t)(pix0 + j) * 64 + nt * 16 + r] = o[j];
}

// ---------------------------------------------------------------------------
extern "C" void kernel_launch(void* const* d_in, const int* in_sizes, int n_in,
                              void* d_out, int out_size, void* d_ws, size_t ws_size,
                              hipStream_t stream)
{
    const float* x  = (const float*)d_in[0];
    const float* wq = (const float*)d_in[1];
    const float* bq = (const float*)d_in[2];
    const float* wk = (const float*)d_in[3];
    const float* bk = (const float*)d_in[4];
    const float* wv = (const float*)d_in[5];
    const float* bv = (const float*)d_in[6];
    const float* wo = (const float*)d_in[7];
    float* out = (float*)d_out;

    // workspace layout (bytes)
    char* base = (char*)d_ws;
    half4*    qhi    = (half4*)(base + 0);          //  393216
    half4*    qlo    = (half4*)(base + 393216);
    half4*    khi    = (half4*)(base + 786432);
    half4*    klo    = (half4*)(base + 1179648);
    _Float16* vT     = (_Float16*)(base + 1572864); //  491520 (8h x 5 planes)
    _Float16* xpad   = (_Float16*)(base + 2064384); //  832000 -> 2896384
    _Float16* attpad = (_Float16*)(base + 2896384); //  416000 -> 3312384
    _Float16* whT    = (_Float16*)(base + 3312384); //  110592 -> 3422976
    _Float16* whoT   = (_Float16*)(base + 3422976); //   36864 -> 3459840
    float*    partA  = (float*)(base + 3459840);    // 3145728 -> 6605568
    float*    partS  = (float*)(base + 6605568);    //  786432 -> 7392000

    hipLaunchKernelGGL(setup_kernel, dim3(60), dim3(256), 0, stream,
                       x, wq, wk, wv, wo, xpad, vT, attpad, whT, whoT);

    hipLaunchKernelGGL(qkv_mfma_kernel, dim3(576), dim3(256), 0, stream,
                       xpad, whT, bq, bk, bv, qhi, qlo, khi, klo, vT);

    hipLaunchKernelGGL(attn_mfma_kernel, dim3(16 * 96), dim3(256), 0, stream,
                       qhi, qlo, khi, klo, vT, partA, partS);

    hipLaunchKernelGGL(attn_reduce_kernel, dim3(192), dim3(256), 0, stream,
                       (const f32x4*)partA, partS, attpad);

    hipLaunchKernelGGL(out_mfma_kernel, dim3(384), dim3(256), 0, stream,
                       attpad, whoT, out);
}

// Round 11
// 78.815 us; speedup vs baseline: 1.3545x; 1.0298x over previous
//
#include <hip/hip_runtime.h>

#define H_IMG 128
#define W_IMG 48
#define CIN   64
#define DM    32
#define NH    8
#define NPIX  6144
#define SSEG  4
#define WPAD  50
#define HPAD  130

// 0.5 (dh^-0.5) * log2(e): folded into wq/bq at convert time
#define Q_SCALE 0.7213475204444817f

typedef _Float16 half4 __attribute__((ext_vector_type(4)));
typedef __fp16   fp16x2 __attribute__((ext_vector_type(2)));
typedef float    f32x4 __attribute__((ext_vector_type(4)));

__device__ __forceinline__ float fexp2(float x) { return __builtin_amdgcn_exp2f(x); }

__device__ __forceinline__ half4 exp_pack(f32x4 s) {
    fp16x2 lo = __builtin_amdgcn_cvt_pkrtz(fexp2(s[0]), fexp2(s[1]));
    fp16x2 hi = __builtin_amdgcn_cvt_pkrtz(fexp2(s[2]), fexp2(s[3]));
    half4 p;
    p[0] = (_Float16)lo[0]; p[1] = (_Float16)lo[1];
    p[2] = (_Float16)hi[0]; p[3] = (_Float16)hi[1];
    return p;
}

// ---------------------------------------------------------------------------
// K0: setup — xpad f16 (zero border), vT ones planes, attpad zero,
// whT[m][32][576] (Q_SCALE folded into m=0), whoT[64][288].
// Weight transposes are one-thread-per-element (fully parallel).
// blocks: [0,26) xpad | 26 vT-ones | [27,53) attpad | [53,269) whT | [269,341) whoT
// ---------------------------------------------------------------------------
__global__ __launch_bounds__(256) void setup_kernel(
    const float* __restrict__ x,
    const float* __restrict__ wq, const float* __restrict__ wk,
    const float* __restrict__ wv, const float* __restrict__ wo,
    _Float16* __restrict__ xpad, _Float16* __restrict__ vT,
    _Float16* __restrict__ attpad,
    _Float16* __restrict__ whT, _Float16* __restrict__ whoT)
{
    const int bid = blockIdx.x;
    const int tid = threadIdx.x;

    if (bid < 26) {                       // xpad: one padded pixel per thread
        const int pp = bid * 256 + tid;
        if (pp < HPAD * WPAD) {
            const int py = pp / WPAD, px = pp % WPAD;
            _Float16* dst = xpad + (size_t)pp * CIN;
            if (py >= 1 && py <= H_IMG && px >= 1 && px <= W_IMG) {
                const float* src = x + ((size_t)(py - 1) * W_IMG + (px - 1)) * CIN;
                #pragma unroll
                for (int c = 0; c < CIN; c += 4) {
                    const float4 v = *reinterpret_cast<const float4*>(src + c);
                    half4 hv = { (_Float16)v.x, (_Float16)v.y, (_Float16)v.z, (_Float16)v.w };
                    *reinterpret_cast<half4*>(dst + c) = hv;
                }
            } else {
                const half4 z = {};
                #pragma unroll
                for (int c = 0; c < CIN; c += 4)
                    *reinterpret_cast<half4*>(dst + c) = z;
            }
        }
    } else if (bid == 26) {               // vT ones planes (h*5+4)
        const int h = tid >> 5, chunk = tid & 31;
        _Float16* dst = vT + ((size_t)(h * 5 + 4)) * NPIX + chunk * (NPIX / 32);
        half4 ones = { (_Float16)1.0f, (_Float16)1.0f, (_Float16)1.0f, (_Float16)1.0f };
        #pragma unroll
        for (int i = 0; i < NPIX / 32; i += 4)
            *reinterpret_cast<half4*>(dst + i) = ones;
    } else if (bid < 53) {                // attpad zero
        const int pp = (bid - 27) * 256 + tid;
        if (pp < HPAD * WPAD) {
            _Float16* dst = attpad + (size_t)pp * DM;
            const half4 z = {};
            #pragma unroll
            for (int c = 0; c < DM; c += 4)
                *reinterpret_cast<half4*>(dst + c) = z;
        }
    } else if (bid < 269) {               // whT: one element per thread
        const int u = (bid - 53) * 256 + tid;
        if (u < 3 * 32 * 576) {
            const int m    = u / 18432;
            const int rem  = u % 18432;
            const int c    = rem / 576;
            const int kidx = rem % 576;
            const int tap  = kidx / 64;
            const int ci   = kidx % 64;
            const float* w = (m == 0) ? wq : (m == 1) ? wk : wv;
            const float s  = (m == 0) ? Q_SCALE : 1.0f;
            whT[u] = (_Float16)(w[(size_t)tap * CIN * DM + (size_t)ci * DM + c] * s);
        }
    } else {                              // whoT: one element per thread
        const int u = (bid - 269) * 256 + tid;
        if (u < 64 * 288) {
            const int c    = u / 288;
            const int kidx = u % 288;
            const int tap  = kidx / 32;
            const int ci   = kidx % 32;
            whoT[u] = (_Float16)wo[(size_t)tap * DM * 64 + (size_t)ci * 64 + c];
        }
    }
}

// ---------------------------------------------------------------------------
// K1: QKV conv as MFMA GEMM.  M=6144 pix, N=32 ch, K=576 (9 taps x 64ci).
// grid = 3m * 2nt * 96; block = 4 waves = 4 pixel tiles.  4 accumulators
// (chains of 9 mfma each).  Epilogue: +bias, emit q/k f16 hi/lo and vT.
// ---------------------------------------------------------------------------
__global__ __launch_bounds__(256) void qkv_mfma_kernel(
    const _Float16* __restrict__ xpad,
    const _Float16* __restrict__ whT,
    const float* __restrict__ bq, const float* __restrict__ bk,
    const float* __restrict__ bv,
    half4* __restrict__ qhi, half4* __restrict__ qlo,
    half4* __restrict__ khi, half4* __restrict__ klo,
    _Float16* __restrict__ vT)
{
    const int m   = __builtin_amdgcn_readfirstlane(blockIdx.x / 192);
    const int nt  = __builtin_amdgcn_readfirstlane((blockIdx.x / 96) % 2);
    const int pg  = blockIdx.x % 96;
    const int wav = __builtin_amdgcn_readfirstlane(threadIdx.x >> 6);
    const int pt  = pg * 4 + wav;                 // pixel tile 0..383
    const int lane = threadIdx.x & 63;
    const int r    = lane & 15;
    const int g16  = lane >> 4;

    const int p  = pt * 16 + r;
    const int y  = p / W_IMG, x0 = p % W_IMG;
    const _Float16* xb = xpad + ((size_t)y * WPAD + x0) * CIN + 4 * g16;

    const int ch = nt * 16 + r;
    const _Float16* wb = whT + ((size_t)(m * 32 + ch)) * 576 + 4 * g16;

    f32x4 acc[4] = {{0.f,0.f,0.f,0.f},{0.f,0.f,0.f,0.f},
                    {0.f,0.f,0.f,0.f},{0.f,0.f,0.f,0.f}};

    #pragma unroll
    for (int dy = 0; dy < 3; ++dy) {
        #pragma unroll
        for (int dx = 0; dx < 3; ++dx) {
            const int toff = (dy * WPAD + dx) * CIN;
            const int k0   = (dy * 3 + dx) * 64;
            #pragma unroll
            for (int cb = 0; cb < 4; ++cb) {
                const half4 xa = *reinterpret_cast<const half4*>(xb + toff + cb * 16);
                const half4 wf = *reinterpret_cast<const half4*>(wb + k0 + cb * 16);
                acc[cb] = __builtin_amdgcn_mfma_f32_16x16x16f16(xa, wf, acc[cb], 0, 0, 0);
            }
        }
    }

    const float* b = (m == 0) ? bq : (m == 1) ? bk : bv;
    const float bias = b[ch] * ((m == 0) ? Q_SCALE : 1.0f);
    f32x4 o = (acc[0] + acc[1]) + (acc[2] + acc[3]);
    #pragma unroll
    for (int j = 0; j < 4; ++j) o[j] += bias;

    const int pix0 = pt * 16 + 4 * g16;
    if (m == 2) {
        const int plane = (ch >> 2) * 5 + (ch & 3);
        half4 hv = { (_Float16)o[0], (_Float16)o[1], (_Float16)o[2], (_Float16)o[3] };
        *reinterpret_cast<half4*>(vT + (size_t)plane * NPIX + pix0) = hv;
    } else {
        _Float16* dhi = (_Float16*)((m == 0) ? qhi : khi);
        _Float16* dlo = (_Float16*)((m == 0) ? qlo : klo);
        const int h = ch >> 2, d = ch & 3;
        #pragma unroll
        for (int j = 0; j < 4; ++j) {
            const float val = o[j];
            const _Float16 hi = (_Float16)val;
            const _Float16 lo = (_Float16)(val - (float)hi);
            const size_t idx = ((size_t)h * NPIX + pix0 + j) * 4 + d;
            dhi[idx] = hi;
            dlo[idx] = lo;
        }
    }
}

// ---------------------------------------------------------------------------
// K2: MFMA local attention (split-K partials), FOUR query tiles per wave.
// grid = 16(hg) x 48; block = 4 waves, same key segment, different tile
// quads -> waves stream identical K/V addresses (L1 temporal sharing).
// Per row: 4 loads feed 8 QK mfma + 8 exp_pack + 8 PV mfma.
// Fused QK k-slot packing (selects by g16, hoisted):
//   A rows (K): {kh, kh, kl, dc};  B cols (Q): {qh, ql, qh, 0}
// V B-fragment: plane min(c,4) of 5-plane vT (col 4 = ones = ssum).
// ---------------------------------------------------------------------------
__global__ __launch_bounds__(256) void attn_mfma_kernel(
    const half4* __restrict__ qhi, const half4* __restrict__ qlo,
    const half4* __restrict__ khi, const half4* __restrict__ klo,
    const _Float16* __restrict__ vT,
    float* __restrict__ partA,     // [SSEG][16hg][3072 q][4]
    float* __restrict__ partS)     // [SSEG][16hg][3072 q]
{
    const int hg   = blockIdx.x / 48;
    const int rest = blockIdx.x % 48;
    const int seg  = __builtin_amdgcn_readfirstlane(rest / 12);
    const int qg   = rest % 12;
    const int wav  = __builtin_amdgcn_readfirstlane(threadIdx.x >> 6);
    const int qt0  = (qg * 4 + wav) * 4;      // tiles qt0..qt0+3
    const int h    = hg >> 1, g = hg & 1;
    const int lane = threadIdx.x & 63;
    const int c    = lane & 15;
    const int g16  = lane >> 4;
    const int c0   = g * 16;

    half4 qf[4] = {{}, {}, {}, {}};
    {
        const half4* qsrc = (g16 == 1) ? qlo : qhi;
        if (g16 < 3) {
            #pragma unroll
            for (int t = 0; t < 4; ++t) {
                const int q  = (qt0 + t) * 16 + c;
                const int qy = q / 24;
                qf[t] = qsrc[h * NPIX + qy * W_IMG + g * 24 + (q - qy * 24)];
            }
        }
    }

    const half4* kb = ((g16 == 2) ? klo : khi) + h * NPIX + c;
    const int vplane = (c < 4) ? c : 4;
    const _Float16* vb = vT + (h * 5 + vplane) * NPIX + 4 * g16;

    const f32x4 zc = {0.f, 0.f, 0.f, 0.f};
    f32x4 o0[4] = {zc, zc, zc, zc};
    f32x4 o1[4] = {zc, zc, zc, zc};

    const int r0 = seg * (H_IMG / SSEG);
    #pragma unroll 2
    for (int r = 0; r < H_IMG / SSEG; ++r) {
        const int koff = (r0 + r) * W_IMG + c0;

        const half4 k0 = kb[koff];
        const half4 k1 = kb[koff + 16];
        const half4 v0 = *reinterpret_cast<const half4*>(vb + koff);
        const half4 v1 = *reinterpret_cast<const half4*>(vb + koff + 16);

        #pragma unroll
        for (int t = 0; t < 4; ++t) {
            const f32x4 s0 = __builtin_amdgcn_mfma_f32_16x16x16f16(k0, qf[t], zc, 0, 0, 0);
            const f32x4 s1 = __builtin_amdgcn_mfma_f32_16x16x16f16(k1, qf[t], zc, 0, 0, 0);
            const half4 p0 = exp_pack(s0);
            const half4 p1 = exp_pack(s1);
            o0[t] = __builtin_amdgcn_mfma_f32_16x16x16f16(p0, v0, o0[t], 0, 0, 0);
            o1[t] = __builtin_amdgcn_mfma_f32_16x16x16f16(p1, v1, o1[t], 0, 0, 0);
        }
    }

    const int base = (seg * 16 + hg) * 3072;
    #pragma unroll
    for (int t = 0; t < 4; ++t) {
        const f32x4 o = o0[t] + o1[t];
        const int qa = base + (qt0 + t) * 16 + g16 * 4;
        if (c < 4) {
            #pragma unroll
            for (int r = 0; r < 4; ++r) partA[(qa + r) * 4 + c] = o[r];
        } else if (c == 4) {
            #pragma unroll
            for (int r = 0; r < 4; ++r) partS[qa + r] = o[r];
        }
    }
}

// ---------------------------------------------------------------------------
// K3: combine split-K partials, normalize, write f16 attpad[py][px][32].
// ---------------------------------------------------------------------------
__global__ __launch_bounds__(256) void attn_reduce_kernel(
    const f32x4* __restrict__ partA4,
    const float* __restrict__ partS,
    _Float16* __restrict__ attpad)
{
    const int idx = blockIdx.x * 256 + threadIdx.x;  // 0..49151
    const int hg  = idx / 3072;
    const int q   = idx % 3072;
    const int h   = hg >> 1, g = hg & 1;

    f32x4 a = {0.f, 0.f, 0.f, 0.f};
    float ss = 0.f;
    #pragma unroll
    for (int s = 0; s < SSEG; ++s) {
        a  += partA4[(s * 16 + hg) * 3072 + q];
        ss += partS [(s * 16 + hg) * 3072 + q];
    }
    const float inv = 1.0f / ss;
    const int qy = q / 24;
    const int qx = g * 24 + (q - qy * 24);
    half4 hv = { (_Float16)(a[0] * inv), (_Float16)(a[1] * inv),
                 (_Float16)(a[2] * inv), (_Float16)(a[3] * inv) };
    *reinterpret_cast<half4*>(
        attpad + ((size_t)(qy + 1) * WPAD + qx + 1) * DM + h * 4) = hv;
}

// ---------------------------------------------------------------------------
// K4: output conv as MFMA GEMM.  M=6144, N=64, K=288 (9 taps x 32ci).
// grid = 4nt * 96; block = 4 waves = 4 pixel tiles.  No bias; f32 out.
// ---------------------------------------------------------------------------
__global__ __launch_bounds__(256) void out_mfma_kernel(
    const _Float16* __restrict__ attpad,
    const _Float16* __restrict__ whoT,
    float* __restrict__ out)
{
    const int nt  = __builtin_amdgcn_readfirstlane(blockIdx.x / 96);
    const int pg  = blockIdx.x % 96;
    const int wav = __builtin_amdgcn_readfirstlane(threadIdx.x >> 6);
    const int pt  = pg * 4 + wav;
    const int lane = threadIdx.x & 63;
    const int r    = lane & 15;
    const int g16  = lane >> 4;

    const int p  = pt * 16 + r;
    const int y  = p / W_IMG, x0 = p % W_IMG;
    const _Float16* ab = attpad + ((size_t)y * WPAD + x0) * DM + 4 * g16;

    const int ch = nt * 16 + r;
    const _Float16* wb = whoT + (size_t)ch * 288 + 4 * g16;

    f32x4 a0 = {0.f, 0.f, 0.f, 0.f}, a1 = {0.f, 0.f, 0.f, 0.f};

    #pragma unroll
    for (int dy = 0; dy < 3; ++dy) {
        #pragma unroll
        for (int dx = 0; dx < 3; ++dx) {
            const int toff = (dy * WPAD + dx) * DM;
            const int k0   = (dy * 3 + dx) * 32;
            #pragma unroll
            for (int cb = 0; cb < 2; ++cb) {
                const half4 xa = *reinterpret_cast<const half4*>(ab + toff + cb * 16);
                const half4 wf = *reinterpret_cast<const half4*>(wb + k0 + cb * 16);
                if (cb & 1)
                    a1 = __builtin_amdgcn_mfma_f32_16x16x16f16(xa, wf, a1, 0, 0, 0);
                else
                    a0 = __builtin_amdgcn_mfma_f32_16x16x16f16(xa, wf, a0, 0, 0, 0);
            }
        }
    }

    const f32x4 o = a0 + a1;
    const int pix0 = pt * 16 + 4 * g16;
    #pragma unroll
    for (int j = 0; j < 4; ++j)
        out[(size_t)(pix0 + j) * 64 + nt * 16 + r] = o[j];
}

// ---------------------------------------------------------------------------
extern "C" void kernel_launch(void* const* d_in, const int* in_sizes, int n_in,
                              void* d_out, int out_size, void* d_ws, size_t ws_size,
                              hipStream_t stream)
{
    const float* x  = (const float*)d_in[0];
    const float* wq = (const float*)d_in[1];
    const float* bq = (const float*)d_in[2];
    const float* wk = (const float*)d_in[3];
    const float* bk = (const float*)d_in[4];
    const float* wv = (const float*)d_in[5];
    const float* bv = (const float*)d_in[6];
    const float* wo = (const float*)d_in[7];
    float* out = (float*)d_out;

    // workspace layout (bytes)
    char* base = (char*)d_ws;
    half4*    qhi    = (half4*)(base + 0);          //  393216
    half4*    qlo    = (half4*)(base + 393216);
    half4*    khi    = (half4*)(base + 786432);
    half4*    klo    = (half4*)(base + 1179648);
    _Float16* vT     = (_Float16*)(base + 1572864); //  491520 (8h x 5 planes)
    _Float16* xpad   = (_Float16*)(base + 2064384); //  832000 -> 2896384
    _Float16* attpad = (_Float16*)(base + 2896384); //  416000 -> 3312384
    _Float16* whT    = (_Float16*)(base + 3312384); //  110592 -> 3422976
    _Float16* whoT   = (_Float16*)(base + 3422976); //   36864 -> 3459840
    float*    partA  = (float*)(base + 3459840);    // 3145728 -> 6605568
    float*    partS  = (float*)(base + 6605568);    //  786432 -> 7392000

    hipLaunchKernelGGL(setup_kernel, dim3(341), dim3(256), 0, stream,
                       x, wq, wk, wv, wo, xpad, vT, attpad, whT, whoT);

    hipLaunchKernelGGL(qkv_mfma_kernel, dim3(576), dim3(256), 0, stream,
                       xpad, whT, bq, bk, bv, qhi, qlo, khi, klo, vT);

    hipLaunchKernelGGL(attn_mfma_kernel, dim3(16 * 48), dim3(256), 0, stream,
                       qhi, qlo, khi, klo, vT, partA, partS);

    hipLaunchKernelGGL(attn_reduce_kernel, dim3(192), dim3(256), 0, stream,
                       (const f32x4*)partA, partS, attpad);

    hipLaunchKernelGGL(out_mfma_kernel, dim3(384), dim3(256), 0, stream,
                       attpad, whoT, out);
}

// Round 12
// 74.619 us; speedup vs baseline: 1.4307x; 1.0562x over previous
//
#include <hip/hip_runtime.h>

#define H_IMG 128
#define W_IMG 48
#define CIN   64
#define DM    32
#define NH    8
#define NPIX  6144
#define WPAD  50
#define HPAD  130

// 0.5 (dh^-0.5) * log2(e): folded into wq/bq at convert time
#define Q_SCALE 0.7213475204444817f

typedef _Float16 half4 __attribute__((ext_vector_type(4)));
typedef __fp16   fp16x2 __attribute__((ext_vector_type(2)));
typedef float    f32x4 __attribute__((ext_vector_type(4)));

__device__ __forceinline__ float fexp2(float x) { return __builtin_amdgcn_exp2f(x); }

__device__ __forceinline__ half4 exp_pack(f32x4 s) {
    fp16x2 lo = __builtin_amdgcn_cvt_pkrtz(fexp2(s[0]), fexp2(s[1]));
    fp16x2 hi = __builtin_amdgcn_cvt_pkrtz(fexp2(s[2]), fexp2(s[3]));
    half4 p;
    p[0] = (_Float16)lo[0]; p[1] = (_Float16)lo[1];
    p[2] = (_Float16)hi[0]; p[3] = (_Float16)hi[1];
    return p;
}

// ---------------------------------------------------------------------------
// K0: setup — xpad f16 (zero border), vT ones planes, attpad zero,
// whT[m][32][576] (Q_SCALE folded into m=0), whoT[64][288] (one elem/thread).
// blocks: [0,26) xpad | 26 vT-ones | [27,53) attpad | [53,269) whT | [269,341) whoT
// ---------------------------------------------------------------------------
__global__ __launch_bounds__(256) void setup_kernel(
    const float* __restrict__ x,
    const float* __restrict__ wq, const float* __restrict__ wk,
    const float* __restrict__ wv, const float* __restrict__ wo,
    _Float16* __restrict__ xpad, _Float16* __restrict__ vT,
    _Float16* __restrict__ attpad,
    _Float16* __restrict__ whT, _Float16* __restrict__ whoT)
{
    const int bid = blockIdx.x;
    const int tid = threadIdx.x;

    if (bid < 26) {                       // xpad: one padded pixel per thread
        const int pp = bid * 256 + tid;
        if (pp < HPAD * WPAD) {
            const int py = pp / WPAD, px = pp % WPAD;
            _Float16* dst = xpad + (size_t)pp * CIN;
            if (py >= 1 && py <= H_IMG && px >= 1 && px <= W_IMG) {
                const float* src = x + ((size_t)(py - 1) * W_IMG + (px - 1)) * CIN;
                #pragma unroll
                for (int c = 0; c < CIN; c += 4) {
                    const float4 v = *reinterpret_cast<const float4*>(src + c);
                    half4 hv = { (_Float16)v.x, (_Float16)v.y, (_Float16)v.z, (_Float16)v.w };
                    *reinterpret_cast<half4*>(dst + c) = hv;
                }
            } else {
                const half4 z = {};
                #pragma unroll
                for (int c = 0; c < CIN; c += 4)
                    *reinterpret_cast<half4*>(dst + c) = z;
            }
        }
    } else if (bid == 26) {               // vT ones planes (h*5+4)
        const int h = tid >> 5, chunk = tid & 31;
        _Float16* dst = vT + ((size_t)(h * 5 + 4)) * NPIX + chunk * (NPIX / 32);
        half4 ones = { (_Float16)1.0f, (_Float16)1.0f, (_Float16)1.0f, (_Float16)1.0f };
        #pragma unroll
        for (int i = 0; i < NPIX / 32; i += 4)
            *reinterpret_cast<half4*>(dst + i) = ones;
    } else if (bid < 53) {                // attpad zero
        const int pp = (bid - 27) * 256 + tid;
        if (pp < HPAD * WPAD) {
            _Float16* dst = attpad + (size_t)pp * DM;
            const half4 z = {};
            #pragma unroll
            for (int c = 0; c < DM; c += 4)
                *reinterpret_cast<half4*>(dst + c) = z;
        }
    } else if (bid < 269) {               // whT: one element per thread
        const int u = (bid - 53) * 256 + tid;
        if (u < 3 * 32 * 576) {
            const int m    = u / 18432;
            const int rem  = u % 18432;
            const int c    = rem / 576;
            const int kidx = rem % 576;
            const int tap  = kidx / 64;
            const int ci   = kidx % 64;
            const float* w = (m == 0) ? wq : (m == 1) ? wk : wv;
            const float s  = (m == 0) ? Q_SCALE : 1.0f;
            whT[u] = (_Float16)(w[(size_t)tap * CIN * DM + (size_t)ci * DM + c] * s);
        }
    } else {                              // whoT: one element per thread
        const int u = (bid - 269) * 256 + tid;
        if (u < 64 * 288) {
            const int c    = u / 288;
            const int kidx = u % 288;
            const int tap  = kidx / 32;
            const int ci   = kidx % 32;
            whoT[u] = (_Float16)wo[(size_t)tap * DM * 64 + (size_t)ci * 64 + c];
        }
    }
}

// ---------------------------------------------------------------------------
// K1: QKV conv as MFMA GEMM.  M=6144 pix, N=32 ch, K=576.  4 accumulators.
// Epilogue: q/k hi/lo fragments transposed through LDS -> coalesced 8B
// stores (half4 per (head,pixel)); V stored directly to 5-plane vT.
// ---------------------------------------------------------------------------
__global__ __launch_bounds__(256) void qkv_mfma_kernel(
    const _Float16* __restrict__ xpad,
    const _Float16* __restrict__ whT,
    const float* __restrict__ bq, const float* __restrict__ bk,
    const float* __restrict__ bv,
    half4* __restrict__ qhi, half4* __restrict__ qlo,
    half4* __restrict__ khi, half4* __restrict__ klo,
    _Float16* __restrict__ vT)
{
    __shared__ _Float16 lt[4][2][16][20];        // [wave][hi/lo][pix][ch+pad]

    const int m   = __builtin_amdgcn_readfirstlane(blockIdx.x / 192);
    const int nt  = __builtin_amdgcn_readfirstlane((blockIdx.x / 96) % 2);
    const int pg  = blockIdx.x % 96;
    const int wav = __builtin_amdgcn_readfirstlane(threadIdx.x >> 6);
    const int pt  = pg * 4 + wav;                 // pixel tile 0..383
    const int lane = threadIdx.x & 63;
    const int r    = lane & 15;
    const int g16  = lane >> 4;

    const int p  = pt * 16 + r;
    const int y  = p / W_IMG, x0 = p % W_IMG;
    const _Float16* xb = xpad + ((size_t)y * WPAD + x0) * CIN + 4 * g16;

    const int ch = nt * 16 + r;
    const _Float16* wb = whT + ((size_t)(m * 32 + ch)) * 576 + 4 * g16;

    f32x4 acc[4] = {{0.f,0.f,0.f,0.f},{0.f,0.f,0.f,0.f},
                    {0.f,0.f,0.f,0.f},{0.f,0.f,0.f,0.f}};

    #pragma unroll
    for (int dy = 0; dy < 3; ++dy) {
        #pragma unroll
        for (int dx = 0; dx < 3; ++dx) {
            const int toff = (dy * WPAD + dx) * CIN;
            const int k0   = (dy * 3 + dx) * 64;
            #pragma unroll
            for (int cb = 0; cb < 4; ++cb) {
                const half4 xa = *reinterpret_cast<const half4*>(xb + toff + cb * 16);
                const half4 wf = *reinterpret_cast<const half4*>(wb + k0 + cb * 16);
                acc[cb] = __builtin_amdgcn_mfma_f32_16x16x16f16(xa, wf, acc[cb], 0, 0, 0);
            }
        }
    }

    const float* b = (m == 0) ? bq : (m == 1) ? bk : bv;
    const float bias = b[ch] * ((m == 0) ? Q_SCALE : 1.0f);
    f32x4 o = (acc[0] + acc[1]) + (acc[2] + acc[3]);
    #pragma unroll
    for (int j = 0; j < 4; ++j) o[j] += bias;

    if (m == 2) {
        const int plane = (ch >> 2) * 5 + (ch & 3);
        const int pix0 = pt * 16 + 4 * g16;
        half4 hv = { (_Float16)o[0], (_Float16)o[1], (_Float16)o[2], (_Float16)o[3] };
        *reinterpret_cast<half4*>(vT + (size_t)plane * NPIX + pix0) = hv;
    } else {
        #pragma unroll
        for (int j = 0; j < 4; ++j) {
            const float val = o[j];
            const _Float16 hi = (_Float16)val;
            const _Float16 lo = (_Float16)(val - (float)hi);
            lt[wav][0][4 * g16 + j][r] = hi;
            lt[wav][1][4 * g16 + j][r] = lo;
        }
        __syncthreads();
        const int p4 = lane & 15;              // pixel within tile
        const int hh = lane >> 4;              // head within nt-half
        const half4 hv = *reinterpret_cast<const half4*>(&lt[wav][0][p4][hh * 4]);
        const half4 lv = *reinterpret_cast<const half4*>(&lt[wav][1][p4][hh * 4]);
        const int h = nt * 4 + hh;
        const size_t idx = (size_t)h * NPIX + pt * 16 + p4;
        ((half4*)((m == 0) ? qhi : khi))[idx] = hv;
        ((half4*)((m == 0) ? qlo : klo))[idx] = lv;
    }
}

// ---------------------------------------------------------------------------
// K2: fused MFMA local attention + split-K reduce + normalize.
// grid = 16(hg) x 48; block = 8 waves (wav = 2*seg + u): seg in [0,4) of 32
// key rows, u in {0,1} selects the tile PAIR (2 query tiles per wave).
// Waves with equal seg (2 per block) stream identical K/V addresses (L1
// sharing).  After the loop, partial O fragments go through LDS; waves with
// seg<2 sum the 4 segments, normalize (bpermute of the ssum column + rcp),
// and write f16 attpad interior directly.  Fused hi/lo QK via k-slot packing:
//   A rows (K): {kh, kh, kl, dc};  B cols (Q): {qh, ql, qh, 0}
// V B-fragment: plane min(c,4) of 5-plane vT (col 4 = ones = ssum).
// ---------------------------------------------------------------------------
__global__ __launch_bounds__(512) void attn_mfma_kernel(
    const half4* __restrict__ qhi, const half4* __restrict__ qlo,
    const half4* __restrict__ khi, const half4* __restrict__ klo,
    const _Float16* __restrict__ vT,
    _Float16* __restrict__ attpad)
{
    __shared__ f32x4 red[8][2][64];

    const int hg  = blockIdx.x / 48;
    const int qq  = blockIdx.x % 48;
    const int h   = hg >> 1, g = hg & 1;
    const int wav = __builtin_amdgcn_readfirstlane(threadIdx.x >> 6);  // 0..7
    const int seg = wav >> 1;
    const int u   = wav & 1;
    const int qt0 = qq * 4 + u * 2;           // tiles qt0, qt0+1
    const int lane = threadIdx.x & 63;
    const int c    = lane & 15;
    const int g16  = lane >> 4;
    const int c0   = g * 16;

    half4 qfA = {}, qfB = {};
    {
        const half4* qsrc = (g16 == 1) ? qlo : qhi;
        const int qa  = qt0 * 16 + c;
        const int qay = qa / 24;
        const int qb  = qa + 16;
        const int qby = qb / 24;
        if (g16 < 3) {
            qfA = qsrc[h * NPIX + qay * W_IMG + g * 24 + (qa - qay * 24)];
            qfB = qsrc[h * NPIX + qby * W_IMG + g * 24 + (qb - qby * 24)];
        }
    }

    const half4* kb = ((g16 == 2) ? klo : khi) + h * NPIX + c;
    const int vplane = (c < 4) ? c : 4;
    const _Float16* vb = vT + (h * 5 + vplane) * NPIX + 4 * g16;

    const f32x4 zc = {0.f, 0.f, 0.f, 0.f};
    f32x4 oA0 = zc, oA1 = zc, oB0 = zc, oB1 = zc;

    const int r0 = seg * 32;
    #pragma unroll 4
    for (int r = 0; r < 32; ++r) {
        const int koff = (r0 + r) * W_IMG + c0;

        const half4 k0 = kb[koff];
        const half4 k1 = kb[koff + 16];
        const half4 v0 = *reinterpret_cast<const half4*>(vb + koff);
        const half4 v1 = *reinterpret_cast<const half4*>(vb + koff + 16);

        const f32x4 sA0 = __builtin_amdgcn_mfma_f32_16x16x16f16(k0, qfA, zc, 0, 0, 0);
        const f32x4 sA1 = __builtin_amdgcn_mfma_f32_16x16x16f16(k1, qfA, zc, 0, 0, 0);
        const f32x4 sB0 = __builtin_amdgcn_mfma_f32_16x16x16f16(k0, qfB, zc, 0, 0, 0);
        const f32x4 sB1 = __builtin_amdgcn_mfma_f32_16x16x16f16(k1, qfB, zc, 0, 0, 0);

        const half4 pA0 = exp_pack(sA0);
        const half4 pA1 = exp_pack(sA1);
        const half4 pB0 = exp_pack(sB0);
        const half4 pB1 = exp_pack(sB1);

        oA0 = __builtin_amdgcn_mfma_f32_16x16x16f16(pA0, v0, oA0, 0, 0, 0);
        oA1 = __builtin_amdgcn_mfma_f32_16x16x16f16(pA1, v1, oA1, 0, 0, 0);
        oB0 = __builtin_amdgcn_mfma_f32_16x16x16f16(pB0, v0, oB0, 0, 0, 0);
        oB1 = __builtin_amdgcn_mfma_f32_16x16x16f16(pB1, v1, oB1, 0, 0, 0);
    }

    red[wav][0][lane] = oA0 + oA1;
    red[wav][1][lane] = oB0 + oB1;
    __syncthreads();

    if (seg < 2) {
        const int t = seg;                     // tile within pair
        f32x4 o = red[u][t][lane];
        o += red[2 + u][t][lane];
        o += red[4 + u][t][lane];
        o += red[6 + u][t][lane];

        const int baddr = (g16 * 16 + 4) << 2; // ssum column lane, in bytes
        f32x4 on;
        #pragma unroll
        for (int r = 0; r < 4; ++r) {
            const float ss = __int_as_float(
                __builtin_amdgcn_ds_bpermute(baddr, __float_as_int(o[r])));
            on[r] = o[r] * __builtin_amdgcn_rcpf(ss);
        }

        if (c < 4) {
            const int qt = qt0 + t;
            #pragma unroll
            for (int r = 0; r < 4; ++r) {
                const int q  = qt * 16 + 4 * g16 + r;
                const int qy = q / 24;
                const int qx = g * 24 + (q - qy * 24);
                attpad[((size_t)(qy + 1) * WPAD + qx + 1) * DM + h * 4 + c] =
                    (_Float16)on[r];
            }
        }
    }
}

// ---------------------------------------------------------------------------
// K3: output conv as MFMA GEMM.  M=6144, N=64, K=288.  No bias; f32 out.
// ---------------------------------------------------------------------------
__global__ __launch_bounds__(256) void out_mfma_kernel(
    const _Float16* __restrict__ attpad,
    const _Float16* __restrict__ whoT,
    float* __restrict__ out)
{
    const int nt  = __builtin_amdgcn_readfirstlane(blockIdx.x / 96);
    const int pg  = blockIdx.x % 96;
    const int wav = __builtin_amdgcn_readfirstlane(threadIdx.x >> 6);
    const int pt  = pg * 4 + wav;
    const int lane = threadIdx.x & 63;
    const int r    = lane & 15;
    const int g16  = lane >> 4;

    const int p  = pt * 16 + r;
    const int y  = p / W_IMG, x0 = p % W_IMG;
    const _Float16* ab = attpad + ((size_t)y * WPAD + x0) * DM + 4 * g16;

    const int ch = nt * 16 + r;
    const _Float16* wb = whoT + (size_t)ch * 288 + 4 * g16;

    f32x4 a0 = {0.f, 0.f, 0.f, 0.f}, a1 = {0.f, 0.f, 0.f, 0.f};

    #pragma unroll
    for (int dy = 0; dy < 3; ++dy) {
        #pragma unroll
        for (int dx = 0; dx < 3; ++dx) {
            const int toff = (dy * WPAD + dx) * DM;
            const int k0   = (dy * 3 + dx) * 32;
            #pragma unroll
            for (int cb = 0; cb < 2; ++cb) {
                const half4 xa = *reinterpret_cast<const half4*>(ab + toff + cb * 16);
                const half4 wf = *reinterpret_cast<const half4*>(wb + k0 + cb * 16);
                if (cb & 1)
                    a1 = __builtin_amdgcn_mfma_f32_16x16x16f16(xa, wf, a1, 0, 0, 0);
                else
                    a0 = __builtin_amdgcn_mfma_f32_16x16x16f16(xa, wf, a0, 0, 0, 0);
            }
        }
    }

    const f32x4 o = a0 + a1;
    const int pix0 = pt * 16 + 4 * g16;
    #pragma unroll
    for (int j = 0; j < 4; ++j)
        out[(size_t)(pix0 + j) * 64 + nt * 16 + r] = o[j];
}

// ---------------------------------------------------------------------------
extern "C" void kernel_launch(void* const* d_in, const int* in_sizes, int n_in,
                              void* d_out, int out_size, void* d_ws, size_t ws_size,
                              hipStream_t stream)
{
    const float* x  = (const float*)d_in[0];
    const float* wq = (const float*)d_in[1];
    const float* bq = (const float*)d_in[2];
    const float* wk = (const float*)d_in[3];
    const float* bk = (const float*)d_in[4];
    const float* wv = (const float*)d_in[5];
    const float* bv = (const float*)d_in[6];
    const float* wo = (const float*)d_in[7];
    float* out = (float*)d_out;

    // workspace layout (bytes)
    char* base = (char*)d_ws;
    half4*    qhi    = (half4*)(base + 0);          //  393216
    half4*    qlo    = (half4*)(base + 393216);
    half4*    khi    = (half4*)(base + 786432);
    half4*    klo    = (half4*)(base + 1179648);
    _Float16* vT     = (_Float16*)(base + 1572864); //  491520 (8h x 5 planes)
    _Float16* xpad   = (_Float16*)(base + 2064384); //  832000 -> 2896384
    _Float16* attpad = (_Float16*)(base + 2896384); //  416000 -> 3312384
    _Float16* whT    = (_Float16*)(base + 3312384); //  110592 -> 3422976
    _Float16* whoT   = (_Float16*)(base + 3422976); //   36864 -> 3459840

    hipLaunchKernelGGL(setup_kernel, dim3(341), dim3(256), 0, stream,
                       x, wq, wk, wv, wo, xpad, vT, attpad, whT, whoT);

    hipLaunchKernelGGL(qkv_mfma_kernel, dim3(576), dim3(256), 0, stream,
                       xpad, whT, bq, bk, bv, qhi, qlo, khi, klo, vT);

    hipLaunchKernelGGL(attn_mfma_kernel, dim3(16 * 48), dim3(512), 0, stream,
                       qhi, qlo, khi, klo, vT, attpad);

    hipLaunchKernelGGL(out_mfma_kernel, dim3(384), dim3(256), 0, stream,
                       attpad, whoT, out);
}

// Round 13
// 68.805 us; speedup vs baseline: 1.5516x; 1.0845x over previous
//
#include <hip/hip_runtime.h>

#define H_IMG 128
#define W_IMG 48
#define CIN   64
#define DM    32
#define NH    8
#define NPIX  6144
#define WPAD  50
#define HPAD  130

// 0.5 (dh^-0.5) * log2(e): folded into wq/bq at convert time
#define Q_SCALE 0.7213475204444817f

typedef _Float16 half4 __attribute__((ext_vector_type(4)));
typedef __fp16   fp16x2 __attribute__((ext_vector_type(2)));
typedef float    f32x4 __attribute__((ext_vector_type(4)));

__device__ __forceinline__ float fexp2(float x) { return __builtin_amdgcn_exp2f(x); }

__device__ __forceinline__ half4 exp_pack(f32x4 s) {
    fp16x2 lo = __builtin_amdgcn_cvt_pkrtz(fexp2(s[0]), fexp2(s[1]));
    fp16x2 hi = __builtin_amdgcn_cvt_pkrtz(fexp2(s[2]), fexp2(s[3]));
    half4 p;
    p[0] = (_Float16)lo[0]; p[1] = (_Float16)lo[1];
    p[2] = (_Float16)hi[0]; p[3] = (_Float16)hi[1];
    return p;
}

// ---------------------------------------------------------------------------
// K0: setup — xpad f16 (zero border), vT ones planes, attpad zero,
// whT[m][32][576] (Q_SCALE folded into m=0), whoT[64][288] (one elem/thread).
// blocks: [0,26) xpad | 26 vT-ones | [27,53) attpad | [53,269) whT | [269,341) whoT
// ---------------------------------------------------------------------------
__global__ __launch_bounds__(256) void setup_kernel(
    const float* __restrict__ x,
    const float* __restrict__ wq, const float* __restrict__ wk,
    const float* __restrict__ wv, const float* __restrict__ wo,
    _Float16* __restrict__ xpad, _Float16* __restrict__ vT,
    _Float16* __restrict__ attpad,
    _Float16* __restrict__ whT, _Float16* __restrict__ whoT)
{
    const int bid = blockIdx.x;
    const int tid = threadIdx.x;

    if (bid < 26) {                       // xpad: one padded pixel per thread
        const int pp = bid * 256 + tid;
        if (pp < HPAD * WPAD) {
            const int py = pp / WPAD, px = pp % WPAD;
            _Float16* dst = xpad + (size_t)pp * CIN;
            if (py >= 1 && py <= H_IMG && px >= 1 && px <= W_IMG) {
                const float* src = x + ((size_t)(py - 1) * W_IMG + (px - 1)) * CIN;
                #pragma unroll
                for (int c = 0; c < CIN; c += 4) {
                    const float4 v = *reinterpret_cast<const float4*>(src + c);
                    half4 hv = { (_Float16)v.x, (_Float16)v.y, (_Float16)v.z, (_Float16)v.w };
                    *reinterpret_cast<half4*>(dst + c) = hv;
                }
            } else {
                const half4 z = {};
                #pragma unroll
                for (int c = 0; c < CIN; c += 4)
                    *reinterpret_cast<half4*>(dst + c) = z;
            }
        }
    } else if (bid == 26) {               // vT ones planes (h*5+4)
        const int h = tid >> 5, chunk = tid & 31;
        _Float16* dst = vT + ((size_t)(h * 5 + 4)) * NPIX + chunk * (NPIX / 32);
        half4 ones = { (_Float16)1.0f, (_Float16)1.0f, (_Float16)1.0f, (_Float16)1.0f };
        #pragma unroll
        for (int i = 0; i < NPIX / 32; i += 4)
            *reinterpret_cast<half4*>(dst + i) = ones;
    } else if (bid < 53) {                // attpad zero
        const int pp = (bid - 27) * 256 + tid;
        if (pp < HPAD * WPAD) {
            _Float16* dst = attpad + (size_t)pp * DM;
            const half4 z = {};
            #pragma unroll
            for (int c = 0; c < DM; c += 4)
                *reinterpret_cast<half4*>(dst + c) = z;
        }
    } else if (bid < 269) {               // whT: one element per thread
        const int u = (bid - 53) * 256 + tid;
        if (u < 3 * 32 * 576) {
            const int m    = u / 18432;
            const int rem  = u % 18432;
            const int c    = rem / 576;
            const int kidx = rem % 576;
            const int tap  = kidx / 64;
            const int ci   = kidx % 64;
            const float* w = (m == 0) ? wq : (m == 1) ? wk : wv;
            const float s  = (m == 0) ? Q_SCALE : 1.0f;
            whT[u] = (_Float16)(w[(size_t)tap * CIN * DM + (size_t)ci * DM + c] * s);
        }
    } else {                              // whoT: one element per thread
        const int u = (bid - 269) * 256 + tid;
        if (u < 64 * 288) {
            const int c    = u / 288;
            const int kidx = u % 288;
            const int tap  = kidx / 32;
            const int ci   = kidx % 32;
            whoT[u] = (_Float16)wo[(size_t)tap * DM * 64 + (size_t)ci * 64 + c];
        }
    }
}

// ---------------------------------------------------------------------------
// K1: QKV conv as MFMA GEMM, dy-split.  grid = (m*2+nt)*384 + pt blocks of
// 3 waves; wave = one dy row of taps (12 mfma, K=192 slice).  Waves 1,2
// deposit partials in LDS; wave 0 sums, adds bias, runs the (validated)
// epilogue: LDS transpose -> coalesced half4 q/k hi/lo stores, or vT planes.
// ---------------------------------------------------------------------------
__global__ __launch_bounds__(192) void qkv_mfma_kernel(
    const _Float16* __restrict__ xpad,
    const _Float16* __restrict__ whT,
    const float* __restrict__ bq, const float* __restrict__ bk,
    const float* __restrict__ bv,
    half4* __restrict__ qhi, half4* __restrict__ qlo,
    half4* __restrict__ khi, half4* __restrict__ klo,
    _Float16* __restrict__ vT)
{
    __shared__ f32x4 redq[2][64];
    __shared__ _Float16 lt[2][16][20];

    const int pt  = blockIdx.x % 384;
    const int ntm = blockIdx.x / 384;
    const int nt  = ntm % 2;
    const int m   = ntm / 2;
    const int wav = __builtin_amdgcn_readfirstlane(threadIdx.x >> 6);  // = dy
    const int lane = threadIdx.x & 63;
    const int r    = lane & 15;
    const int g16  = lane >> 4;

    const int p  = pt * 16 + r;
    const int y  = p / W_IMG, x0 = p % W_IMG;
    const _Float16* xb = xpad + ((size_t)y * WPAD + x0) * CIN + 4 * g16;

    const int ch = nt * 16 + r;
    const _Float16* wb = whT + ((size_t)(m * 32 + ch)) * 576 + 4 * g16;

    f32x4 acc[4] = {{0.f,0.f,0.f,0.f},{0.f,0.f,0.f,0.f},
                    {0.f,0.f,0.f,0.f},{0.f,0.f,0.f,0.f}};

    const int dy = wav;
    #pragma unroll
    for (int dx = 0; dx < 3; ++dx) {
        const int toff = (dy * WPAD + dx) * CIN;
        const int k0   = (dy * 3 + dx) * 64;
        #pragma unroll
        for (int cb = 0; cb < 4; ++cb) {
            const half4 xa = *reinterpret_cast<const half4*>(xb + toff + cb * 16);
            const half4 wf = *reinterpret_cast<const half4*>(wb + k0 + cb * 16);
            acc[cb] = __builtin_amdgcn_mfma_f32_16x16x16f16(xa, wf, acc[cb], 0, 0, 0);
        }
    }

    f32x4 o = (acc[0] + acc[1]) + (acc[2] + acc[3]);

    if (wav > 0) redq[wav - 1][lane] = o;
    __syncthreads();
    if (wav != 0) return;

    o += redq[0][lane] + redq[1][lane];

    const float* b = (m == 0) ? bq : (m == 1) ? bk : bv;
    const float bias = b[ch] * ((m == 0) ? Q_SCALE : 1.0f);
    #pragma unroll
    for (int j = 0; j < 4; ++j) o[j] += bias;

    if (m == 2) {
        const int plane = (ch >> 2) * 5 + (ch & 3);
        const int pix0 = pt * 16 + 4 * g16;
        half4 hv = { (_Float16)o[0], (_Float16)o[1], (_Float16)o[2], (_Float16)o[3] };
        *reinterpret_cast<half4*>(vT + (size_t)plane * NPIX + pix0) = hv;
    } else {
        #pragma unroll
        for (int j = 0; j < 4; ++j) {
            const float val = o[j];
            const _Float16 hi = (_Float16)val;
            const _Float16 lo = (_Float16)(val - (float)hi);
            lt[0][4 * g16 + j][r] = hi;
            lt[1][4 * g16 + j][r] = lo;
        }
        // same-wave LDS readback (lockstep; compiler inserts lgkmcnt)
        const int p4 = lane & 15;              // pixel within tile
        const int hh = lane >> 4;              // head within nt-half
        const half4 hv = *reinterpret_cast<const half4*>(&lt[0][p4][hh * 4]);
        const half4 lv = *reinterpret_cast<const half4*>(&lt[1][p4][hh * 4]);
        const int h = nt * 4 + hh;
        const size_t idx = (size_t)h * NPIX + pt * 16 + p4;
        ((half4*)((m == 0) ? qhi : khi))[idx] = hv;
        ((half4*)((m == 0) ? qlo : klo))[idx] = lv;
    }
}

// ---------------------------------------------------------------------------
// K2: fused MFMA local attention + split-K reduce + normalize, SSEG=8.
// grid = 16(hg) x 48; block = 16 waves (wav = u*8 + seg): seg in [0,8) of 16
// key rows, u in {0,1} selects the tile PAIR (2 query tiles per wave).
// Two waves per (seg) stream identical K/V addresses.  After the loop,
// partial O fragments go through LDS; waves 0..3 sum the 8 segments of one
// tile each, normalize (bpermute of ssum column + rcp), write f16 attpad.
// Fused hi/lo QK k-slot packing: A(K)={kh,kh,kl,dc}, B(Q)={qh,ql,qh,0}.
// V B-fragment: plane min(c,4) of 5-plane vT (col 4 = ones = ssum).
// ---------------------------------------------------------------------------
__global__ __launch_bounds__(1024) void attn_mfma_kernel(
    const half4* __restrict__ qhi, const half4* __restrict__ qlo,
    const half4* __restrict__ khi, const half4* __restrict__ klo,
    const _Float16* __restrict__ vT,
    _Float16* __restrict__ attpad)
{
    __shared__ f32x4 red[16][2][64];   // 32 KB

    const int hg  = blockIdx.x / 48;
    const int qq  = blockIdx.x % 48;
    const int h   = hg >> 1, g = hg & 1;
    const int wav = __builtin_amdgcn_readfirstlane(threadIdx.x >> 6);  // 0..15
    const int seg = wav & 7;
    const int u   = wav >> 3;
    const int qt0 = qq * 4 + u * 2;           // tiles qt0, qt0+1
    const int lane = threadIdx.x & 63;
    const int c    = lane & 15;
    const int g16  = lane >> 4;
    const int c0   = g * 16;

    half4 qfA = {}, qfB = {};
    {
        const half4* qsrc = (g16 == 1) ? qlo : qhi;
        const int qa  = qt0 * 16 + c;
        const int qay = qa / 24;
        const int qb  = qa + 16;
        const int qby = qb / 24;
        if (g16 < 3) {
            qfA = qsrc[h * NPIX + qay * W_IMG + g * 24 + (qa - qay * 24)];
            qfB = qsrc[h * NPIX + qby * W_IMG + g * 24 + (qb - qby * 24)];
        }
    }

    const half4* kb = ((g16 == 2) ? klo : khi) + h * NPIX + c;
    const int vplane = (c < 4) ? c : 4;
    const _Float16* vb = vT + (h * 5 + vplane) * NPIX + 4 * g16;

    const f32x4 zc = {0.f, 0.f, 0.f, 0.f};
    f32x4 oA0 = zc, oA1 = zc, oB0 = zc, oB1 = zc;

    const int r0 = seg * 16;
    #pragma unroll 4
    for (int r = 0; r < 16; ++r) {
        const int koff = (r0 + r) * W_IMG + c0;

        const half4 k0 = kb[koff];
        const half4 k1 = kb[koff + 16];
        const half4 v0 = *reinterpret_cast<const half4*>(vb + koff);
        const half4 v1 = *reinterpret_cast<const half4*>(vb + koff + 16);

        const f32x4 sA0 = __builtin_amdgcn_mfma_f32_16x16x16f16(k0, qfA, zc, 0, 0, 0);
        const f32x4 sA1 = __builtin_amdgcn_mfma_f32_16x16x16f16(k1, qfA, zc, 0, 0, 0);
        const f32x4 sB0 = __builtin_amdgcn_mfma_f32_16x16x16f16(k0, qfB, zc, 0, 0, 0);
        const f32x4 sB1 = __builtin_amdgcn_mfma_f32_16x16x16f16(k1, qfB, zc, 0, 0, 0);

        const half4 pA0 = exp_pack(sA0);
        const half4 pA1 = exp_pack(sA1);
        const half4 pB0 = exp_pack(sB0);
        const half4 pB1 = exp_pack(sB1);

        oA0 = __builtin_amdgcn_mfma_f32_16x16x16f16(pA0, v0, oA0, 0, 0, 0);
        oA1 = __builtin_amdgcn_mfma_f32_16x16x16f16(pA1, v1, oA1, 0, 0, 0);
        oB0 = __builtin_amdgcn_mfma_f32_16x16x16f16(pB0, v0, oB0, 0, 0, 0);
        oB1 = __builtin_amdgcn_mfma_f32_16x16x16f16(pB1, v1, oB1, 0, 0, 0);
    }

    red[wav][0][lane] = oA0 + oA1;
    red[wav][1][lane] = oB0 + oB1;
    __syncthreads();

    if (wav < 4) {
        const int u2  = wav >> 1;              // pair group
        const int t01 = wav & 1;               // tile within pair
        f32x4 o = red[u2 * 8 + 0][t01][lane];
        #pragma unroll
        for (int s = 1; s < 8; ++s)
            o += red[u2 * 8 + s][t01][lane];

        const int baddr = (g16 * 16 + 4) << 2; // ssum column lane, in bytes
        f32x4 on;
        #pragma unroll
        for (int r = 0; r < 4; ++r) {
            const float ss = __int_as_float(
                __builtin_amdgcn_ds_bpermute(baddr, __float_as_int(o[r])));
            on[r] = o[r] * __builtin_amdgcn_rcpf(ss);
        }

        if (c < 4) {
            const int qt = qq * 4 + u2 * 2 + t01;
            #pragma unroll
            for (int r = 0; r < 4; ++r) {
                const int q  = qt * 16 + 4 * g16 + r;
                const int qy = q / 24;
                const int qx = g * 24 + (q - qy * 24);
                attpad[((size_t)(qy + 1) * WPAD + qx + 1) * DM + h * 4 + c] =
                    (_Float16)on[r];
            }
        }
    }
}

// ---------------------------------------------------------------------------
// K3: output conv as MFMA GEMM, dy-split.  grid = nt*384 + pt blocks of
// 3 waves (wave = dy, 6 mfma each); LDS-sum, wave 0 stores f32 out.
// ---------------------------------------------------------------------------
__global__ __launch_bounds__(192) void out_mfma_kernel(
    const _Float16* __restrict__ attpad,
    const _Float16* __restrict__ whoT,
    float* __restrict__ out)
{
    __shared__ f32x4 redo[2][64];

    const int pt  = blockIdx.x % 384;
    const int nt  = blockIdx.x / 384;        // 0..3
    const int wav = __builtin_amdgcn_readfirstlane(threadIdx.x >> 6);  // = dy
    const int lane = threadIdx.x & 63;
    const int r    = lane & 15;
    const int g16  = lane >> 4;

    const int p  = pt * 16 + r;
    const int y  = p / W_IMG, x0 = p % W_IMG;
    const _Float16* ab = attpad + ((size_t)y * WPAD + x0) * DM + 4 * g16;

    const int ch = nt * 16 + r;
    const _Float16* wb = whoT + (size_t)ch * 288 + 4 * g16;

    f32x4 a0 = {0.f, 0.f, 0.f, 0.f}, a1 = {0.f, 0.f, 0.f, 0.f};

    const int dy = wav;
    #pragma unroll
    for (int dx = 0; dx < 3; ++dx) {
        const int toff = (dy * WPAD + dx) * DM;
        const int k0   = (dy * 3 + dx) * 32;
        const half4 xa0 = *reinterpret_cast<const half4*>(ab + toff);
        const half4 wf0 = *reinterpret_cast<const half4*>(wb + k0);
        a0 = __builtin_amdgcn_mfma_f32_16x16x16f16(xa0, wf0, a0, 0, 0, 0);
        const half4 xa1 = *reinterpret_cast<const half4*>(ab + toff + 16);
        const half4 wf1 = *reinterpret_cast<const half4*>(wb + k0 + 16);
        a1 = __builtin_amdgcn_mfma_f32_16x16x16f16(xa1, wf1, a1, 0, 0, 0);
    }

    f32x4 o = a0 + a1;
    if (wav > 0) redo[wav - 1][lane] = o;
    __syncthreads();
    if (wav != 0) return;

    o += redo[0][lane] + redo[1][lane];

    const int pix0 = pt * 16 + 4 * g16;
    #pragma unroll
    for (int j = 0; j < 4; ++j)
        out[(size_t)(pix0 + j) * 64 + nt * 16 + r] = o[j];
}

// ---------------------------------------------------------------------------
extern "C" void kernel_launch(void* const* d_in, const int* in_sizes, int n_in,
                              void* d_out, int out_size, void* d_ws, size_t ws_size,
                              hipStream_t stream)
{
    const float* x  = (const float*)d_in[0];
    const float* wq = (const float*)d_in[1];
    const float* bq = (const float*)d_in[2];
    const float* wk = (const float*)d_in[3];
    const float* bk = (const float*)d_in[4];
    const float* wv = (const float*)d_in[5];
    const float* bv = (const float*)d_in[6];
    const float* wo = (const float*)d_in[7];
    float* out = (float*)d_out;

    // workspace layout (bytes)
    char* base = (char*)d_ws;
    half4*    qhi    = (half4*)(base + 0);          //  393216
    half4*    qlo    = (half4*)(base + 393216);
    half4*    khi    = (half4*)(base + 786432);
    half4*    klo    = (half4*)(base + 1179648);
    _Float16* vT     = (_Float16*)(base + 1572864); //  491520 (8h x 5 planes)
    _Float16* xpad   = (_Float16*)(base + 2064384); //  832000 -> 2896384
    _Float16* attpad = (_Float16*)(base + 2896384); //  416000 -> 3312384
    _Float16* whT    = (_Float16*)(base + 3312384); //  110592 -> 3422976
    _Float16* whoT   = (_Float16*)(base + 3422976); //   36864 -> 3459840

    hipLaunchKernelGGL(setup_kernel, dim3(341), dim3(256), 0, stream,
                       x, wq, wk, wv, wo, xpad, vT, attpad, whT, whoT);

    hipLaunchKernelGGL(qkv_mfma_kernel, dim3(2304), dim3(192), 0, stream,
                       xpad, whT, bq, bk, bv, qhi, qlo, khi, klo, vT);

    hipLaunchKernelGGL(attn_mfma_kernel, dim3(16 * 48), dim3(1024), 0, stream,
                       qhi, qlo, khi, klo, vT, attpad);

    hipLaunchKernelGGL(out_mfma_kernel, dim3(4 * 384), dim3(192), 0, stream,
                       attpad, whoT, out);
}